// Round 4
// baseline (61.997 us; speedup 1.0000x reference)
//
#include <hip/hip_runtime.h>
#include <hip/hip_cooperative_groups.h>

namespace cg = cooperative_groups;

#define NB   4
#define NPIX 65536        // 256*256
#define ACCD 24
#define NC   576          // ACCD*ACCD
#define BIGV 1000000

struct Ws {
  int bin_min[NB * 2];
  int bin_max[NB * 2];
  int4 part[64];          // per-block partials {mn0,mn1,mx0,mx1}
  unsigned acc[NB * NC];
  int table[NB * NC];
};

__device__ __forceinline__ int2 bin_of(float ox, float oy, int x, int y) {
  // /16 == *0.0625f exactly; rintf = round half to even, matching jnp.round
  return make_int2((int)rintf(((float)x + ox) * 0.0625f),
                   (int)rintf(((float)y + oy) * 0.0625f));
}

// One cooperative kernel, 64 blocks x 1024 threads = 1 thread / 4 pixels.
// Registers carry per-pixel bins across all phases (inputs read exactly once).
__global__ void __launch_bounds__(1024) k_fused(const float* __restrict__ off,
                                                const int* __restrict__ fg,
                                                int* __restrict__ out, Ws* ws) {
  cg::grid_group grid = cg::this_grid();
  const int tid = threadIdx.x;
  const int lane = tid & 63, wid = tid >> 6;           // 16 waves/block
  const int b = blockIdx.x >> 4;                       // 16 blocks/batch
  const int n0 = ((blockIdx.x & 15) << 12) | (tid << 2);

  __shared__ int s4[16][4];
  __shared__ unsigned hist[NC];
  __shared__ int cnt[NC];
  __shared__ int rowsum[NC];
  __shared__ int plist[NC];
  __shared__ int sh_tbl[NC];
  __shared__ float wmax[16];
  __shared__ int wcnt[16];
  __shared__ int woff[17];
  __shared__ float thrsh;
  __shared__ int Psh;

  // ---- Phase A: load once, bins -> registers, block min/max partials, zero acc
  const float4 ox4 = *(const float4*)&off[(b * 2 + 0) * NPIX + n0];
  const float4 oy4 = *(const float4*)&off[(b * 2 + 1) * NPIX + n0];
  const int4 fg4 = *(const int4*)&fg[b * NPIX + n0];
  const float oxs[4] = {ox4.x, ox4.y, ox4.z, ox4.w};
  const float oys[4] = {oy4.x, oy4.y, oy4.z, oy4.w};
  const int fgs[4] = {fg4.x, fg4.y, fg4.z, fg4.w};
  int bx[4], by[4];
  int mn0 = BIGV, mn1 = BIGV, mx0 = -BIGV, mx1 = -BIGV;
#pragma unroll
  for (int u = 0; u < 4; ++u) {
    const int n = n0 + u;
    const int2 bb = bin_of(oxs[u], oys[u], n & 255, n >> 8);
    bx[u] = bb.x; by[u] = bb.y;
    if (fgs[u] != 0) {
      mn0 = min(mn0, bb.x); mn1 = min(mn1, bb.y);
      mx0 = max(mx0, bb.x); mx1 = max(mx1, bb.y);
    }
  }
  for (int o = 32; o > 0; o >>= 1) {
    mn0 = min(mn0, __shfl_xor(mn0, o, 64));
    mn1 = min(mn1, __shfl_xor(mn1, o, 64));
    mx0 = max(mx0, __shfl_xor(mx0, o, 64));
    mx1 = max(mx1, __shfl_xor(mx1, o, 64));
  }
  if (lane == 0) { s4[wid][0] = mn0; s4[wid][1] = mn1; s4[wid][2] = mx0; s4[wid][3] = mx1; }
  __syncthreads();
  if (tid == 0) {
    int a0 = s4[0][0], a1 = s4[0][1], c0 = s4[0][2], c1 = s4[0][3];
    for (int w = 1; w < 16; ++w) {
      a0 = min(a0, s4[w][0]); a1 = min(a1, s4[w][1]);
      c0 = max(c0, s4[w][2]); c1 = max(c1, s4[w][3]);
    }
    ws->part[blockIdx.x] = make_int4(a0, a1, c0, c1);
  }
  {
    const int g = blockIdx.x * 1024 + tid;
    if (g < NB * NC) ws->acc[g] = 0u;
  }
  grid.sync();

  // ---- Phase B: 4 blocks reduce their batch's 16 partials -> bin_min/max
  if (blockIdx.x < NB && tid < 16) {
    const int4 p = ws->part[blockIdx.x * 16 + tid];
    int a0 = p.x, a1 = p.y, c0 = p.z, c1 = p.w;
    for (int o = 8; o > 0; o >>= 1) {            // lanes 0..15 only
      a0 = min(a0, __shfl_xor(a0, o, 64));
      a1 = min(a1, __shfl_xor(a1, o, 64));
      c0 = max(c0, __shfl_xor(c0, o, 64));
      c1 = max(c1, __shfl_xor(c1, o, 64));
    }
    if (tid == 0) {
      ws->bin_min[blockIdx.x * 2 + 0] = a0; ws->bin_min[blockIdx.x * 2 + 1] = a1;
      ws->bin_max[blockIdx.x * 2 + 0] = c0; ws->bin_max[blockIdx.x * 2 + 1] = c1;
    }
  }
  grid.sync();

  // ---- Phase C: LDS histogram, then few global atomics
  const int m0 = ws->bin_min[b * 2 + 0], m1 = ws->bin_min[b * 2 + 1];
  if (tid < NC) hist[tid] = 0u;
  __syncthreads();
#pragma unroll
  for (int u = 0; u < 4; ++u) {
    if (fgs[u] != 0) {
      const int c0 = min(max(bx[u] - m0, 0), ACCD - 1);
      const int c1 = min(max(by[u] - m1, 0), ACCD - 1);
      atomicAdd(&hist[c0 * ACCD + c1], 1u);
    }
  }
  __syncthreads();
  if (tid < NC) {
    const unsigned v = hist[tid];
    if (v) atomicAdd(&ws->acc[b * NC + tid], v);
  }
  grid.sync();

  // ---- Phase D: blocks 0..3 do smoothing + threshold + peaks + label table
  if (blockIdx.x < NB) {
    const int pb = blockIdx.x;
    const bool act = tid < NC;
    const int ci = act ? tid / ACCD : 0, cj = act ? tid % ACCD : 0;

    if (act) cnt[tid] = (int)ws->acc[pb * NC + tid];
    __syncthreads();
    if (act) {
      int s = 0;
      const int j0 = max(cj - 6, 0), j1 = min(cj + 6, ACCD - 1);
      for (int jj = j0; jj <= j1; ++jj) s += cnt[ci * ACCD + jj];
      rowsum[tid] = s;
    }
    __syncthreads();
    float sm = 0.f;
    if (act) {
      int sum = 0;
      const int i0 = max(ci - 6, 0), i1 = min(ci + 6, ACCD - 1);
      for (int ii = i0; ii <= i1; ++ii) sum += rowsum[ii * ACCD + cj];
      sm = (float)sum * (1.0f / 169.0f);
      const int vm0 = ws->bin_max[pb * 2 + 0] - ws->bin_min[pb * 2 + 0] + 1;
      const int vm1 = ws->bin_max[pb * 2 + 1] - ws->bin_min[pb * 2 + 1] + 1;
      if (ci >= vm0 || cj >= vm1) sm = 0.f;
    }
    float m = sm;
    for (int o = 32; o > 0; o >>= 1) m = fmaxf(m, __shfl_xor(m, o, 64));
    if (lane == 0) wmax[wid] = m;
    __syncthreads();
    if (tid == 0) {
      float mm = wmax[0];
      for (int w = 1; w < 16; ++w) mm = fmaxf(mm, wmax[w]);
      thrsh = fmaxf(mm * 0.3f, 50.0f);
    }
    __syncthreads();

    const bool flag = act && (sm >= thrsh);
    const unsigned long long mask = __ballot(flag);
    const int rank = (int)__popcll(mask & ((1ull << lane) - 1ull));
    if (lane == 0) wcnt[wid] = (int)__popcll(mask);
    __syncthreads();
    if (tid == 0) {
      woff[0] = 0;
      for (int w = 0; w < 16; ++w) woff[w + 1] = woff[w] + wcnt[w];
      Psh = woff[16];
    }
    __syncthreads();
    if (flag) plist[woff[wid] + rank] = (ci << 8) | cj;
    __syncthreads();

    // argmin w/ first-occurrence tie-break == min of key (d<<10)|k; d exact int
    const int P = Psh;
    if (act) {
      int bestkey = 0x7fffffff;
      int k = 0;
      for (; k + 7 < P; k += 8) {
#pragma unroll
        for (int u = 0; u < 8; ++u) {
          const int pk = plist[k + u];
          const int di = ci - (pk >> 8), dj = cj - (pk & 255);
          const int key = ((di * di + dj * dj) << 10) | (k + u);
          bestkey = min(bestkey, key);
        }
      }
      for (; k < P; ++k) {
        const int pk = plist[k];
        const int di = ci - (pk >> 8), dj = cj - (pk & 255);
        const int key = ((di * di + dj * dj) << 10) | k;
        bestkey = min(bestkey, key);
      }
      ws->table[pb * NC + tid] = (P > 0) ? ((bestkey & 1023) + 1) : 0;
    }
  }
  grid.sync();

  // ---- Phase E: stage table in LDS, write labels from phase-A registers
  if (tid < NC) sh_tbl[tid] = ws->table[b * NC + tid];
  __syncthreads();
  int lab[4];
#pragma unroll
  for (int u = 0; u < 4; ++u) {
    lab[u] = 0;
    if (fgs[u] != 0) {
      const int s0 = min(max(bx[u] - m0, 0), ACCD - 1);
      const int s1 = min(max(by[u] - m1, 0), ACCD - 1);
      lab[u] = sh_tbl[s0 * ACCD + s1];
    }
  }
  *(int4*)&out[b * NPIX + n0] = make_int4(lab[0], lab[1], lab[2], lab[3]);
}

extern "C" void kernel_launch(void* const* d_in, const int* in_sizes, int n_in,
                              void* d_out, int out_size, void* d_ws, size_t ws_size,
                              hipStream_t stream) {
  const float* off = (const float*)d_in[0];
  const int* fg = (const int*)d_in[1];
  int* out = (int*)d_out;
  Ws* ws = (Ws*)d_ws;

  void* args[] = {(void*)&off, (void*)&fg, (void*)&out, (void*)&ws};
  hipLaunchCooperativeKernel((void*)k_fused, dim3(64), dim3(1024), args, 0, stream);
}

// Round 5
// 25.767 us; speedup vs baseline: 2.4061x; 2.4061x over previous
//
#include <hip/hip_runtime.h>

#define NB   4
#define NPIX 65536        // 256*256
#define ACCD 24
#define NC   576          // ACCD*ACCD
#define HD   32           // raw-bin histogram dim
#define HC   1024         // HD*HD
#define HOFF 8            // raw-bin offset into histogram space
#define BIGV 1000000

// ws layout: unsigned part[64][HC]  (per-block partial histograms; 256 KB)

__device__ __forceinline__ int2 bin_of(float ox, float oy, int x, int y) {
  // /16 == *0.0625f exactly; rintf = round half to even, matching jnp.round
  return make_int2((int)rintf(((float)x + ox) * 0.0625f),
                   (int)rintf(((float)y + oy) * 0.0625f));
}

// K1: raw-bin LDS histogram per block -> distinct partial slot (no atomics on
// global, no init kernel, no bin_min dependency).
__global__ void __launch_bounds__(1024) k_hist(const float* __restrict__ off,
                                               const int* __restrict__ fg,
                                               unsigned* __restrict__ part) {
  const int tid = threadIdx.x;
  const int b = blockIdx.x >> 4;                       // 16 blocks/batch
  const int n0 = ((blockIdx.x & 15) << 12) | (tid << 2);

  __shared__ unsigned hist[HC];
  hist[tid] = 0u;
  __syncthreads();

  const float4 ox4 = *(const float4*)&off[(b * 2 + 0) * NPIX + n0];
  const float4 oy4 = *(const float4*)&off[(b * 2 + 1) * NPIX + n0];
  const int4 fg4 = *(const int4*)&fg[b * NPIX + n0];
  const float oxs[4] = {ox4.x, ox4.y, ox4.z, ox4.w};
  const float oys[4] = {oy4.x, oy4.y, oy4.z, oy4.w};
  const int fgs[4] = {fg4.x, fg4.y, fg4.z, fg4.w};
#pragma unroll
  for (int u = 0; u < 4; ++u) {
    if (fgs[u] != 0) {
      const int n = n0 + u;
      const int2 bb = bin_of(oxs[u], oys[u], n & 255, n >> 8);
      const int h0 = min(max(bb.x + HOFF, 0), HD - 1);  // clamp never active for these inputs
      const int h1 = min(max(bb.y + HOFF, 0), HD - 1);
      atomicAdd(&hist[h0 * HD + h1], 1u);
    }
  }
  __syncthreads();
  part[blockIdx.x * HC + tid] = hist[tid];
}

// K2: per block -- sum 16 partials (fixed order, deterministic), min/max from
// marginals, smooth+threshold+peaks+table in LDS (redundant per batch, cheap),
// then label own 4096-pixel slice.
__global__ void __launch_bounds__(1024) k_finish(const float* __restrict__ off,
                                                 const int* __restrict__ fg,
                                                 const unsigned* __restrict__ part,
                                                 int* __restrict__ out) {
  const int tid = threadIdx.x;
  const int lane = tid & 63, wid = tid >> 6;           // 16 waves
  const int b = blockIdx.x >> 4;
  const int n0 = ((blockIdx.x & 15) << 12) | (tid << 2);

  __shared__ int hist[HC];
  __shared__ int cnt[NC];
  __shared__ int rowsum[NC];
  __shared__ int plist[NC];
  __shared__ int sh_tbl[NC];
  __shared__ int wred[16][4];
  __shared__ float wmax[16];
  __shared__ int wcnt[16];
  __shared__ int woff[17];
  __shared__ int mm4[4];      // rmin, rmax, cmin, cmax (histogram space)
  __shared__ float thrsh;
  __shared__ int Psh;

  // sum partials for this batch (fixed order k=0..15 -> deterministic)
  int v = 0;
#pragma unroll
  for (int k = 0; k < 16; ++k) v += (int)part[(b * 16 + k) * HC + tid];
  hist[tid] = v;

  // bin_min/max from marginals: min/max row & col with nonzero count
  int rmn = v > 0 ? (tid >> 5) : BIGV, rmx = v > 0 ? (tid >> 5) : -BIGV;
  int cmn = v > 0 ? (tid & 31) : BIGV, cmx = v > 0 ? (tid & 31) : -BIGV;
  for (int o = 32; o > 0; o >>= 1) {
    rmn = min(rmn, __shfl_xor(rmn, o, 64));
    rmx = max(rmx, __shfl_xor(rmx, o, 64));
    cmn = min(cmn, __shfl_xor(cmn, o, 64));
    cmx = max(cmx, __shfl_xor(cmx, o, 64));
  }
  if (lane == 0) { wred[wid][0] = rmn; wred[wid][1] = rmx; wred[wid][2] = cmn; wred[wid][3] = cmx; }
  __syncthreads();
  if (tid == 0) {
    int a = wred[0][0], bb_ = wred[0][1], c = wred[0][2], d = wred[0][3];
    for (int w = 1; w < 16; ++w) {
      a = min(a, wred[w][0]); bb_ = max(bb_, wred[w][1]);
      c = min(c, wred[w][2]); d = max(d, wred[w][3]);
    }
    mm4[0] = a; mm4[1] = bb_; mm4[2] = c; mm4[3] = d;
  }
  __syncthreads();
  const int rmin = mm4[0], rmax = mm4[1], cmin = mm4[2], cmax = mm4[3];

  // build 24x24 window of the histogram at (rmin, cmin)
  const bool act = tid < NC;
  const int ci = act ? tid / ACCD : 0, cj = act ? tid % ACCD : 0;
  if (act) {
    const int ri = rmin + ci, rj = cmin + cj;
    cnt[tid] = ((unsigned)ri < HD && (unsigned)rj < HD) ? hist[ri * HD + rj] : 0;
  }
  __syncthreads();

  // separable 13x13 box sum
  if (act) {
    int s = 0;
    const int j0 = max(cj - 6, 0), j1 = min(cj + 6, ACCD - 1);
    for (int jj = j0; jj <= j1; ++jj) s += cnt[ci * ACCD + jj];
    rowsum[tid] = s;
  }
  __syncthreads();
  float sm = 0.f;
  if (act) {
    int sum = 0;
    const int i0 = max(ci - 6, 0), i1 = min(ci + 6, ACCD - 1);
    for (int ii = i0; ii <= i1; ++ii) sum += rowsum[ii * ACCD + cj];
    sm = (float)sum * (1.0f / 169.0f);
    const int vm0 = rmax - rmin + 1, vm1 = cmax - cmin + 1;  // tight extents
    if (ci >= vm0 || cj >= vm1) sm = 0.f;
  }

  // block max -> threshold
  float m = sm;
  for (int o = 32; o > 0; o >>= 1) m = fmaxf(m, __shfl_xor(m, o, 64));
  if (lane == 0) wmax[wid] = m;
  __syncthreads();
  if (tid == 0) {
    float mm = wmax[0];
    for (int w = 1; w < 16; ++w) mm = fmaxf(mm, wmax[w]);
    thrsh = fmaxf(mm * 0.3f, 50.0f);
  }
  __syncthreads();

  // row-major peak compaction (ballot + prefix)
  const bool flag = act && (sm >= thrsh);
  const unsigned long long mask = __ballot(flag);
  const int rank = (int)__popcll(mask & ((1ull << lane) - 1ull));
  if (lane == 0) wcnt[wid] = (int)__popcll(mask);
  __syncthreads();
  if (tid == 0) {
    woff[0] = 0;
    for (int w = 0; w < 16; ++w) woff[w + 1] = woff[w] + wcnt[w];
    Psh = woff[16];
  }
  __syncthreads();
  if (flag) plist[woff[wid] + rank] = (ci << 8) | cj;
  __syncthreads();

  // nearest peak: argmin w/ first-occurrence tie-break == min key (d<<10)|k
  const int P = Psh;
  if (act) {
    int bestkey = 0x7fffffff;
    int k = 0;
    for (; k + 7 < P; k += 8) {
#pragma unroll
      for (int u = 0; u < 8; ++u) {
        const int pk = plist[k + u];
        const int di = ci - (pk >> 8), dj = cj - (pk & 255);
        const int key = ((di * di + dj * dj) << 10) | (k + u);
        bestkey = min(bestkey, key);
      }
    }
    for (; k < P; ++k) {
      const int pk = plist[k];
      const int di = ci - (pk >> 8), dj = cj - (pk & 255);
      const int key = ((di * di + dj * dj) << 10) | k;
      bestkey = min(bestkey, key);
    }
    sh_tbl[tid] = (P > 0) ? ((bestkey & 1023) + 1) : 0;
  }
  __syncthreads();

  // label this block's pixel slice
  const float4 ox4 = *(const float4*)&off[(b * 2 + 0) * NPIX + n0];
  const float4 oy4 = *(const float4*)&off[(b * 2 + 1) * NPIX + n0];
  const int4 fg4 = *(const int4*)&fg[b * NPIX + n0];
  const float oxs[4] = {ox4.x, ox4.y, ox4.z, ox4.w};
  const float oys[4] = {oy4.x, oy4.y, oy4.z, oy4.w};
  const int fgs[4] = {fg4.x, fg4.y, fg4.z, fg4.w};
  int lab[4];
#pragma unroll
  for (int u = 0; u < 4; ++u) {
    lab[u] = 0;
    if (fgs[u] != 0) {
      const int n = n0 + u;
      const int2 bb = bin_of(oxs[u], oys[u], n & 255, n >> 8);
      const int h0 = min(max(bb.x + HOFF, 0), HD - 1);
      const int h1 = min(max(bb.y + HOFF, 0), HD - 1);
      const int s0 = min(max(h0 - rmin, 0), ACCD - 1);  // == clip(bins - bin_min)
      const int s1 = min(max(h1 - cmin, 0), ACCD - 1);
      lab[u] = sh_tbl[s0 * ACCD + s1];
    }
  }
  *(int4*)&out[b * NPIX + n0] = make_int4(lab[0], lab[1], lab[2], lab[3]);
}

extern "C" void kernel_launch(void* const* d_in, const int* in_sizes, int n_in,
                              void* d_out, int out_size, void* d_ws, size_t ws_size,
                              hipStream_t stream) {
  const float* off = (const float*)d_in[0];
  const int* fg = (const int*)d_in[1];
  int* out = (int*)d_out;
  unsigned* part = (unsigned*)d_ws;

  k_hist<<<64, 1024, 0, stream>>>(off, fg, part);
  k_finish<<<64, 1024, 0, stream>>>(off, fg, part, out);
}